// Round 5
// baseline (150.946 us; speedup 1.0000x reference)
//
#include <hip/hip_runtime.h>
#include <hip/hip_bf16.h>

#define BATCH 4
#define CH 256
#define CRD 32
#define NN 4096

typedef __bf16 bf16x8 __attribute__((ext_vector_type(8)));
typedef float floatx4 __attribute__((ext_vector_type(4)));
typedef float floatx16 __attribute__((ext_vector_type(16)));
typedef unsigned short ushort4v __attribute__((ext_vector_type(4)));
typedef unsigned short ushort8v __attribute__((ext_vector_type(8)));
typedef unsigned int uint2v __attribute__((ext_vector_type(2)));
typedef unsigned int uint4v __attribute__((ext_vector_type(4)));

// Native bf16 convert: lowers to v_cvt_pk_bf16_f32 (RNE).
static __device__ __forceinline__ unsigned short f2bf(float f) {
    __bf16 h = (__bf16)f;
    return __builtin_bit_cast(unsigned short, h);
}
static __device__ __forceinline__ float bf2f(unsigned short h) {
    return __uint_as_float((unsigned int)h << 16);
}

// ---------------------------------------------------------------------------
// Fragment layout conventions (32x32x16 bf16 MFMA), verified R2-R8:
//   A[m][k]: lane l holds m = l&31, k = (l>>5)*8 + j
//   B[k][n]: lane l holds n = l&31, k = (l>>5)*8 + j
//   D      : lane l holds col = l&31, row = (r&3) + 8*(r>>2) + 4*(l>>5)
// Frag-major storage: addr = (tile*64 + (d32&31) + 32*((d16>>3)&1))*8 + (d16&7)
//
// REGISTER-BUDGET RULE (paid R3, R8, R10): never demand occupancy beyond
// ~20% headroom over the estimated VGPR need.
//
// R13 (this round): key-split 4 -> 2, exploiting fixed-shift softmax.
//   Non-attn time has been flat ~98us for 5 rounds while attn fell 67->51;
//   arithmetic floor for qkv+out+wconv is ~45us. Biggest identified slack:
//   Opart volume (33.6MB written + 33.6 read) and out's combine VALU
//   (~1100 ops/thread dependency-chained into each MFMA).
//   With all partials sharing m = M0, combine = (Wo@O0 + Wo@O1)/(l0+l1):
//   * attn: ks=2, grid (64,2,4)=512 blocks x 16 its. Total MFMA/VALU/V-
//     traffic invariant; Opart write HALVES (16.8MB); ml stores l only.
//     XCD remap: each XCD owns one (ks,b) -> ~1.2MB working set.
//   * out: EXACT 2-chain MFMA combine (Opart bf16 straight to MFMA),
//     post-GEMM (a0+a1)*rL. 64 acc VGPR (~100 tot, 20%+ headroom under
//     the (256,2)=128 cap — NOT R10's 128-acc spill mode). No unpack VALU.
//   * qkv, wconv frozen for attribution.
// ---------------------------------------------------------------------------

// ---------------------------------------------------------------------------
// K0: weight prep. mb0 = Wq pre-scaled by softmax_scale * log2(e).
// ---------------------------------------------------------------------------
__global__ __launch_bounds__(256) void wconv_kernel(
    const float* __restrict__ Wq, const float* __restrict__ Wk,
    const float* __restrict__ Wv, const float* __restrict__ Wo,
    unsigned short* __restrict__ What, unsigned short* __restrict__ WobF)
{
    const int o = blockIdx.x;
    const int t = threadIdx.x;   // input channel c
    float scale = 1.0f;
    const float* src;
    if (o < 32)      { src = Wq + o * 256;
                       scale = 0.17677669529663687f * 1.4426950408889634f; }
    else if (o < 64) { src = Wk + (o - 32) * 256; }
    else             { src = Wv + (o - 64) * 256; }
    const int mb = o >> 5;
    const size_t idx = ((size_t)(mb * 16 + (t >> 4)) * 64
                        + (o & 31) + 32 * ((t >> 3) & 1)) * 8 + (t & 7);
    What[idx] = f2bf(src[t] * scale);
    if (o < 256) {
        const size_t i2 = ((size_t)((o >> 5) * 16 + (t >> 4)) * 64
                           + (o & 31) + 32 * ((t >> 3) & 1)) * 8 + (t & 7);
        WobF[i2] = f2bf(Wo[o * 256 + t]);
    }
}

// Exchange rg-quad packs across the h halves (lanes +-32) -> one full 16B
// lane-contiguous store. Layout in memory bit-identical to scalar path.
static __device__ __forceinline__ uint4v hmerge(
    const ushort4v& xp, const ushort4v& yp, int h)
{
    uint2v xd = __builtin_bit_cast(uint2v, xp);
    uint2v yd = __builtin_bit_cast(uint2v, yp);
    unsigned int px0 = (unsigned int)__shfl_xor((int)xd[0], 32);
    unsigned int px1 = (unsigned int)__shfl_xor((int)xd[1], 32);
    unsigned int py0 = (unsigned int)__shfl_xor((int)yd[0], 32);
    unsigned int py1 = (unsigned int)__shfl_xor((int)yd[1], 32);
    uint4v st;
    st[0] = h ? py0 : xd[0];
    st[1] = h ? py1 : xd[1];
    st[2] = h ? yd[0] : px0;
    st[3] = h ? yd[1] : px1;
    return st;
}

// ---------------------------------------------------------------------------
// K1: QKV as MFMA GEMM. grid (128 n-tiles of 32, 4 b), block 256 (4 waves).
// V staged through xf-LDS (XOR-swizzled) -> dense b128 vh writes.
// ---------------------------------------------------------------------------
__global__ __launch_bounds__(256, 2) void qkv_kernel(
    const float* __restrict__ x, const unsigned short* __restrict__ What,
    unsigned short* __restrict__ qh, unsigned short* __restrict__ kh,
    unsigned short* __restrict__ vh)
{
    __shared__ __align__(16) unsigned short xf[16 * 512];  // 16 KB; reused for V

    const int t = threadIdx.x;
    const int w = t >> 6;
    const int l = t & 63;
    const int l31 = l & 31;
    const int h = l >> 5;
    const int nt = blockIdx.x, b = blockIdx.y;
    const int n0 = nt * 32;

    // ---- stage: thread (n = t&31, cq = t>>5); per pass 4 c-rows -> b64 ----
    {
        const float* xb = x + (size_t)(b * CH) * NN + n0;
        const int n = t & 31;
        const int cq = t >> 5;           // 0..7
        #pragma unroll
        for (int p = 0; p < 8; ++p) {
            int c = p * 32 + cq * 4;
            float v0 = xb[(size_t)(c + 0) * NN + n];
            float v1 = xb[(size_t)(c + 1) * NN + n];
            float v2 = xb[(size_t)(c + 2) * NN + n];
            float v3 = xb[(size_t)(c + 3) * NN + n];
            ushort4v u4;
            u4[0] = f2bf(v0); u4[1] = f2bf(v1); u4[2] = f2bf(v2); u4[3] = f2bf(v3);
            int addr = ((2 * p + (cq >> 2)) * 64 + n + 32 * ((cq >> 1) & 1)) * 8
                       + 4 * (cq & 1);
            *(ushort4v*)&xf[addr] = u4;
        }
    }
    __syncthreads();

    const int mb0 = w, mb1 = w + 4, mb2 = w + 8;   // mb2 valid only for w<2
    floatx16 acc0, acc1, acc2;
    #pragma unroll
    for (int i = 0; i < 16; ++i) { acc0[i] = 0.f; acc1[i] = 0.f; acc2[i] = 0.f; }

    for (int kblk = 0; kblk < 16; ++kblk) {
        bf16x8 bf = *(const bf16x8*)&xf[kblk * 512 + l * 8];
        bf16x8 a0 = *(const bf16x8*)(What + ((size_t)(mb0 * 16 + kblk) * 64 + l) * 8);
        bf16x8 a1 = *(const bf16x8*)(What + ((size_t)(mb1 * 16 + kblk) * 64 + l) * 8);
        acc0 = __builtin_amdgcn_mfma_f32_32x32x16_bf16(a0, bf, acc0, 0, 0, 0);
        acc1 = __builtin_amdgcn_mfma_f32_32x32x16_bf16(a1, bf, acc1, 0, 0, 0);
        if (w < 2) {
            bf16x8 a2 = *(const bf16x8*)(What + ((size_t)(mb2 * 16 + kblk) * 64 + l) * 8);
            acc2 = __builtin_amdgcn_mfma_f32_32x32x16_bf16(a2, bf, acc2, 0, 0, 0);
        }
    }

    // q/k: full-line b128 stores via h-exchange (layout bit-identical)
    auto store_qk = [&](unsigned short* dst, const floatx16& a) {
        size_t base = (size_t)(b * 128 + nt) * 1024;
        #pragma unroll
        for (int sb = 0; sb < 2; ++sb) {
            ushort4v xp, yp;
            #pragma unroll
            for (int i = 0; i < 4; ++i) {
                xp[i] = f2bf(a[8 * sb + i]);
                yp[i] = f2bf(a[8 * sb + 4 + i]);
            }
            uint4v st = hmerge(xp, yp, h);
            *(uint4v*)(dst + base + (size_t)sb * 512 + (size_t)l * 8) = st;
        }
    };

    if (w == 0)      store_qk(qh, acc0);
    else if (w == 1) store_qk(kh, acc0);

    __syncthreads();   // all xf (GEMM B-frag) reads done; reuse xf for V

    // v staged to LDS in vh-chunk layout with XOR bank swizzle.
    auto store_v_lds = [&](int cblk, const floatx16& a) {
        const int chunk = cblk * 2 + (l31 >> 4);
        const int hib = (l31 >> 3) & 1;
        #pragma unroll
        for (int r = 0; r < 16; ++r) {
            int rowo = (r & 3) + 8 * (r >> 2) + 4 * h;
            int unit = chunk * 64 + hib * 32 + rowo;
            int pu = unit ^ ((unit >> 5) & 7);
            xf[pu * 8 + (l31 & 7)] = f2bf(a[r]);
        }
    };

    if (w >= 2) store_v_lds(w - 2, acc0);
    store_v_lds(w + 2, acc1);
    if (w < 2) store_v_lds(w + 6, acc2);

    __syncthreads();

    // copy LDS -> vh: 16 chunks x 1KB, each contiguous in global. Dense b128.
    #pragma unroll
    for (int p = 0; p < 4; ++p) {
        int Lu = p * 256 + t;                 // logical unit 0..1023
        int pu = Lu ^ ((Lu >> 5) & 7);
        uint4v d = *(const uint4v*)&xf[pu * 8];
        int chunk = Lu >> 6;
        int cblk = chunk >> 1, sub = chunk & 1;
        size_t dst = (((size_t)b * 8 + cblk) * 256 + nt * 2 + sub) * 512
                     + (size_t)(Lu & 63) * 8;
        *(uint4v*)(vh + dst) = d;
    }
}

// ---------------------------------------------------------------------------
// K2: flash attention, Q-tile 64, 8 waves (512 thr), key-split 2.
// grid (64 qt-pairs, 2 ks, 4 b) = 512 blocks; XCD remap: combo = lin&7 ->
// each XCD owns exactly one (ks,b); working set (V-half 1MB + K-half 128KB)
// L2-resident. Fixed-shift softmax P = 2^(S-12); one barrier/iter; 16 its.
// Wave w: S for key-slice (w&3), q-half (w>>2); PV for cblk w, both halves.
// ---------------------------------------------------------------------------
#define SM_M0 12.0f

__global__ __launch_bounds__(512, 4) void attn_kernel(
    const unsigned short* __restrict__ qh, const unsigned short* __restrict__ kh,
    const unsigned short* __restrict__ vh, unsigned short* __restrict__ Opart,
    float* __restrict__ ml)
{
    __shared__ unsigned short p_lds[2 * 16 * 64 * 8];   // 32 KB, double-buffered
    __shared__ float psum_s[8][32];

    const int t = threadIdx.x;
    const int w = t >> 6;          // 0..7
    const int l = t & 63;
    const int l31 = l & 31;
    const int h = l >> 5;
    const int wk = w & 3;          // key sub-slice
    const int hq = w >> 2;         // q-half for S phase

    // XCD remap: lin in [0,512); combo = lin&7 = XCD id; bijective.
    const int lin = blockIdx.x + ((int)blockIdx.y << 6) + ((int)blockIdx.z << 7);
    const int combo = lin & 7;
    const int gp = lin >> 3;                          // 0..63 qt-pair
    const int ks = combo & 1;
    const int b  = combo >> 1;
    const int g0 = 2 * gp, g1 = 2 * gp + 1;

    const unsigned short* qB = qh + (size_t)(b * 128 + (hq ? g1 : g0)) * 1024;
    const unsigned short* kB = kh + (size_t)b * 128 * 1024;
    const unsigned short* vB = vh + (size_t)b * 8 * 256 * 512;

    // resident Q B-frags (this wave's q-half)
    bf16x8 qf0 = *(const bf16x8*)(qB + l * 8);
    bf16x8 qf1 = *(const bf16x8*)(qB + 512 + l * 8);

    // prefetch K A-frags for iter 0 (key-tile = ks*64 + it*4 + wk)
    bf16x8 kf0 = *(const bf16x8*)(kB + (size_t)(ks * 64 + wk) * 1024 + l * 8);
    bf16x8 kf1 = *(const bf16x8*)(kB + (size_t)(ks * 64 + wk) * 1024 + 512 + l * 8);

    float l_loc = 0.f;
    floatx16 acc_a, acc_b;        // cblk w, q-halves a/b
    #pragma unroll
    for (int i = 0; i < 16; ++i) { acc_a[i] = 0.f; acc_b[i] = 0.f; }

    for (int it = 0; it < 16; ++it) {
        const int pbase = (it & 1) << 13;            // 8192 ushorts per buffer

        // ---- phase 1: scores S[32k][32q] for (key-slice wk, q-half hq) ----
        floatx16 sacc;
        #pragma unroll
        for (int i = 0; i < 16; ++i) sacc[i] = 0.f;
        __builtin_amdgcn_s_setprio(1);
        sacc = __builtin_amdgcn_mfma_f32_32x32x16_bf16(kf0, qf0, sacc, 0, 0, 0);
        sacc = __builtin_amdgcn_mfma_f32_32x32x16_bf16(kf1, qf1, sacc, 0, 0, 0);
        __builtin_amdgcn_s_setprio(0);

        // ---- phase 2: P = 2^(S - M0); per-lane l accumulation; pack ----
        float pv[16];
        #pragma unroll
        for (int r = 0; r < 16; ++r) pv[r] = __builtin_exp2f(sacc[r] - SM_M0);
        float s0 = (pv[0] + pv[1]) + (pv[2] + pv[3]);
        float s1 = (pv[4] + pv[5]) + (pv[6] + pv[7]);
        float s2 = (pv[8] + pv[9]) + (pv[10] + pv[11]);
        float s3 = (pv[12] + pv[13]) + (pv[14] + pv[15]);
        l_loc += (s0 + s1) + (s2 + s3);
        // P tile = hq*8 + 2*wk + (rg>>1); within-tile unit l31 + 32*(rg&1)
        #pragma unroll
        for (int rg = 0; rg < 4; ++rg) {
            ushort4v pk;
            #pragma unroll
            for (int i = 0; i < 4; ++i) pk[i] = f2bf(pv[rg * 4 + i]);
            int idx = pbase
                    + ((hq * 8 + 2 * wk + (rg >> 1)) * 64
                       + l31 + 32 * (rg & 1)) * 8 + 4 * h;
            *(ushort4v*)&p_lds[idx] = pk;
        }
        // prefetch next K (in flight across the barrier)
        if (it < 15) {
            const unsigned short* kn = kB + (size_t)(ks * 64 + (it + 1) * 4 + wk) * 1024;
            kf0 = *(const bf16x8*)(kn + l * 8);
            kf1 = *(const bf16x8*)(kn + 512 + l * 8);
        }
        // preload ALL 8 V slices for cblk w (independent of p_lds; the
        // L2 latency hides under the barrier + first LDS reads)
        const unsigned short* v0b = vB + ((size_t)w * 256 + (ks * 16 + it) * 8) * 512;
        bf16x8 va0 = *(const bf16x8*)(v0b + 0 * 512 + l * 8);
        bf16x8 va1 = *(const bf16x8*)(v0b + 1 * 512 + l * 8);
        bf16x8 va2 = *(const bf16x8*)(v0b + 2 * 512 + l * 8);
        bf16x8 va3 = *(const bf16x8*)(v0b + 3 * 512 + l * 8);
        bf16x8 va4 = *(const bf16x8*)(v0b + 4 * 512 + l * 8);
        bf16x8 va5 = *(const bf16x8*)(v0b + 5 * 512 + l * 8);
        bf16x8 va6 = *(const bf16x8*)(v0b + 6 * 512 + l * 8);
        bf16x8 va7 = *(const bf16x8*)(v0b + 7 * 512 + l * 8);

        __syncthreads();   // p_lds[pbase] visible; prev-buffer reads long done

        // ---- phase 3: PV; each V frag feeds BOTH q-half P tiles ----
        bf16x8 pa = *(const bf16x8*)&p_lds[pbase + l * 8];
        bf16x8 pb = *(const bf16x8*)&p_lds[pbase + 4096 + l * 8];
        #pragma unroll
        for (int s = 0; s < 8; ++s) {
            bf16x8 vcur = (s == 0) ? va0 : (s == 1) ? va1 : (s == 2) ? va2
                        : (s == 3) ? va3 : (s == 4) ? va4 : (s == 5) ? va5
                        : (s == 6) ? va6 : va7;
            bf16x8 pa_n, pb_n;
            if (s < 7) {
                pa_n = *(const bf16x8*)&p_lds[pbase + ((s + 1) * 64 + l) * 8];
                pb_n = *(const bf16x8*)&p_lds[pbase + 4096 + ((s + 1) * 64 + l) * 8];
            }
            __builtin_amdgcn_s_setprio(1);
            acc_a = __builtin_amdgcn_mfma_f32_32x32x16_bf16(vcur, pa, acc_a, 0, 0, 0);
            acc_b = __builtin_amdgcn_mfma_f32_32x32x16_bf16(vcur, pb, acc_b, 0, 0, 0);
            __builtin_amdgcn_s_setprio(0);
            pa = pa_n; pb = pb_n;
        }
    }

    // ---- cross-wave l reduction (once): waves 0-3 -> half a, 4-7 -> b ----
    float lt = l_loc + __shfl_xor(l_loc, 32);
    if (h == 0) psum_s[w][l31] = lt;
    __syncthreads();

    if (w == 0 && h == 0) {
        float l_run = (psum_s[0][l31] + psum_s[1][l31])
                    + (psum_s[2][l31] + psum_s[3][l31]);
        ml[((size_t)(b * 128 + g0) * 2 + ks) * 32 + l31] = l_run;
    }
    if (w == 4 && h == 0) {
        float l_run = (psum_s[4][l31] + psum_s[5][l31])
                    + (psum_s[6][l31] + psum_s[7][l31]);
        ml[((size_t)(b * 128 + g1) * 2 + ks) * 32 + l31] = l_run;
    }

    // ---- epilogue: full-line b128 stores (sP = 2*cblk + sb; cblk = w) ----
    unsigned short* opa = Opart + ((size_t)((b * 128 + g0) * 2 + ks)) * 8192;
    unsigned short* opb = Opart + ((size_t)((b * 128 + g1) * 2 + ks)) * 8192;
    #pragma unroll
    for (int ct = 0; ct < 2; ++ct) {
        const floatx16& a = ct ? acc_b : acc_a;
        unsigned short* op = ct ? opb : opa;
        #pragma unroll
        for (int sb = 0; sb < 2; ++sb) {
            ushort4v xp, yp;
            #pragma unroll
            for (int i = 0; i < 4; ++i) {
                xp[i] = f2bf(a[8 * sb + i]);
                yp[i] = f2bf(a[8 * sb + 4 + i]);
            }
            uint4v st = hmerge(xp, yp, h);
            int sP = 2 * w + sb;
            *(uint4v*)(op + ((size_t)sP * 64 + l) * 8) = st;
        }
    }
}

// ---------------------------------------------------------------------------
// K3: Wo GEMM as TWO exact MFMA chains (one per key-split partial, Opart
// bf16 fed straight to MFMA — zero combine VALU in the loop), then
// (a0+a1) * 1/(l0+l1) post-GEMM (valid since all partials share m = M0),
// + gamma*out + x. 64 acc VGPR, ~100 total (20%+ headroom under 128 cap).
// ---------------------------------------------------------------------------
__global__ __launch_bounds__(256, 2) void out_kernel(
    const unsigned short* __restrict__ Opart, const float* __restrict__ ml,
    const unsigned short* __restrict__ WobF, const float* __restrict__ x,
    const float* __restrict__ gamma, float* __restrict__ out)
{
    const int t = threadIdx.x;
    const int w = t >> 6;
    const int l = t & 63;
    const int l31 = l & 31;
    const int h = l >> 5;
    const int qt = blockIdx.x, b = blockIdx.y;

    const size_t slot2 = (size_t)(b * 128 + qt) * 2;
    float l0 = ml[(slot2 + 0) * 32 + l31];
    float l1 = ml[(slot2 + 1) * 32 + l31];
    float rL = 1.0f / (l0 + l1);     // per-lane: D-layout col = l31 = query

    const unsigned short* o0 = Opart + (slot2 + 0) * 8192;
    const unsigned short* o1 = Opart + (slot2 + 1) * 8192;

    floatx16 a0[2], a1[2];
    #pragma unroll
    for (int m = 0; m < 2; ++m)
        #pragma unroll
        for (int i = 0; i < 16; ++i) { a0[m][i] = 0.f; a1[m][i] = 0.f; }

    #pragma unroll 2
    for (int s = 0; s < 16; ++s) {
        bf16x8 f0 = *(const bf16x8*)(o0 + (s * 64 + l) * 8);
        bf16x8 f1 = *(const bf16x8*)(o1 + (s * 64 + l) * 8);
        #pragma unroll
        for (int m = 0; m < 2; ++m) {
            int mt = 2 * w + m;
            bf16x8 af = *(const bf16x8*)(WobF + ((size_t)(mt * 16 + s) * 64 + l) * 8);
            a0[m] = __builtin_amdgcn_mfma_f32_32x32x16_bf16(af, f0, a0[m], 0, 0, 0);
            a1[m] = __builtin_amdgcn_mfma_f32_32x32x16_bf16(af, f1, a1[m], 0, 0, 0);
        }
    }

    const float gm = gamma[0];
    #pragma unroll
    for (int m = 0; m < 2; ++m)
        #pragma unroll
        for (int r = 0; r < 16; ++r) {
            float v = (a0[m][r] + a1[m][r]) * rL;
            int o = (2 * w + m) * 32 + (r & 3) + 8 * (r >> 2) + 4 * h;
            int n = qt * 32 + l31;
            size_t oi = ((size_t)(b * 256 + o)) * NN + n;
            out[oi] = gm * v + x[oi];
        }
}

// ---------------------------------------------------------------------------
extern "C" void kernel_launch(void* const* d_in, const int* in_sizes, int n_in,
                              void* d_out, int out_size, void* d_ws, size_t ws_size,
                              hipStream_t stream)
{
    const float* x     = (const float*)d_in[0];
    const float* Wq    = (const float*)d_in[1];
    const float* Wk    = (const float*)d_in[2];
    const float* Wv    = (const float*)d_in[3];
    const float* Wo    = (const float*)d_in[4];
    const float* gamma = (const float*)d_in[5];
    float* out = (float*)d_out;

    char* wsb = (char*)d_ws;
    unsigned short* qh    = (unsigned short*)(wsb);                          // 1 MB
    unsigned short* kh    = (unsigned short*)(wsb + (1u << 20));             // 1 MB
    unsigned short* vh    = (unsigned short*)(wsb + (2u << 20));             // 8 MB
    unsigned short* What  = (unsigned short*)(wsb + (10u << 20));            // 160 KB
    unsigned short* WobF  = (unsigned short*)(wsb + (10u << 20) + (256u << 10)); // 128 KB
    unsigned short* Opart = (unsigned short*)(wsb + (11u << 20));            // 16.8 MB (ks=2)
    float*          ml    = (float*)         (wsb + (45u << 20));            // 128 KB

    wconv_kernel<<<320, 256, 0, stream>>>(Wq, Wk, Wv, Wo, What, WobF);

    dim3 g1(128, BATCH);
    qkv_kernel<<<g1, 256, 0, stream>>>(x, What, qh, kh, vh);

    dim3 g2(64, 2, BATCH);
    attn_kernel<<<g2, 512, 0, stream>>>(qh, kh, vh, Opart, ml);

    dim3 g3(128, BATCH);
    out_kernel<<<g3, 256, 0, stream>>>(Opart, ml, WobF, x, gamma, out);
}

// Round 6
// 136.769 us; speedup vs baseline: 1.1037x; 1.1037x over previous
//
#include <hip/hip_runtime.h>
#include <hip/hip_bf16.h>

#define BATCH 4
#define CH 256
#define CRD 32
#define NN 4096

typedef __bf16 bf16x8 __attribute__((ext_vector_type(8)));
typedef float floatx4 __attribute__((ext_vector_type(4)));
typedef float floatx16 __attribute__((ext_vector_type(16)));
typedef unsigned short ushort4v __attribute__((ext_vector_type(4)));
typedef unsigned short ushort8v __attribute__((ext_vector_type(8)));
typedef unsigned int uint2v __attribute__((ext_vector_type(2)));
typedef unsigned int uint4v __attribute__((ext_vector_type(4)));

// Native bf16 convert: lowers to v_cvt_pk_bf16_f32 (RNE).
static __device__ __forceinline__ unsigned short f2bf(float f) {
    __bf16 h = (__bf16)f;
    return __builtin_bit_cast(unsigned short, h);
}
static __device__ __forceinline__ float bf2f(unsigned short h) {
    return __uint_as_float((unsigned int)h << 16);
}

// ---------------------------------------------------------------------------
// Fragment layout conventions (32x32x16 bf16 MFMA), verified R2-R8:
//   A[m][k]: lane l holds m = l&31, k = (l>>5)*8 + j
//   B[k][n]: lane l holds n = l&31, k = (l>>5)*8 + j
//   D      : lane l holds col = l&31, row = (r&3) + 8*(r>>2) + 4*(l>>5)
// Frag-major storage: addr = (tile*64 + (d32&31) + 32*((d16>>3)&1))*8 + (d16&7)
//
// REGISTER-BUDGET RULE (paid R3, R8, R10): never demand occupancy beyond
// ~20% headroom over the estimated VGPR need.
//
// LEDGER (R5 lesson): V traffic = (#q-tile blocks) x (V rows scanned) —
// INVARIANT to the key-split factor. Only Q-TILE SIZE reduces it (R4:
// 32->64 halved it, -7us). ks=2 kept only for the smaller Opart.
//
// R14 (this round): qkv/out only; attn+wconv FROZEN at R5 for attribution.
//   Non-attn has been ~98us flat for 6 rounds; both qkv and out ran at
//   2 waves/SIMD (512 blocks x 4 waves) — TLP-starved memory kernels.
//   * qkv: 640-thr blocks (10 waves), ONE MFMA chain per wave (mb 0..9),
//     20 waves/CU (5/SIMD). Staging over 512 threads (16 loads each).
//   * out: m-split grid (128,2,4); wave = 1 m-tile, 2 exact chains,
//     32 acc VGPR, 4 waves/SIMD. mhalf twins land on the same XCD
//     (lin ids differ by 128 = 0 mod 8) -> shared Opart in L2.
// ---------------------------------------------------------------------------

// ---------------------------------------------------------------------------
// K0: weight prep. mb0 = Wq pre-scaled by softmax_scale * log2(e).
// ---------------------------------------------------------------------------
__global__ __launch_bounds__(256) void wconv_kernel(
    const float* __restrict__ Wq, const float* __restrict__ Wk,
    const float* __restrict__ Wv, const float* __restrict__ Wo,
    unsigned short* __restrict__ What, unsigned short* __restrict__ WobF)
{
    const int o = blockIdx.x;
    const int t = threadIdx.x;   // input channel c
    float scale = 1.0f;
    const float* src;
    if (o < 32)      { src = Wq + o * 256;
                       scale = 0.17677669529663687f * 1.4426950408889634f; }
    else if (o < 64) { src = Wk + (o - 32) * 256; }
    else             { src = Wv + (o - 64) * 256; }
    const int mb = o >> 5;
    const size_t idx = ((size_t)(mb * 16 + (t >> 4)) * 64
                        + (o & 31) + 32 * ((t >> 3) & 1)) * 8 + (t & 7);
    What[idx] = f2bf(src[t] * scale);
    if (o < 256) {
        const size_t i2 = ((size_t)((o >> 5) * 16 + (t >> 4)) * 64
                           + (o & 31) + 32 * ((t >> 3) & 1)) * 8 + (t & 7);
        WobF[i2] = f2bf(Wo[o * 256 + t]);
    }
}

// Exchange rg-quad packs across the h halves (lanes +-32) -> one full 16B
// lane-contiguous store. Layout in memory bit-identical to scalar path.
static __device__ __forceinline__ uint4v hmerge(
    const ushort4v& xp, const ushort4v& yp, int h)
{
    uint2v xd = __builtin_bit_cast(uint2v, xp);
    uint2v yd = __builtin_bit_cast(uint2v, yp);
    unsigned int px0 = (unsigned int)__shfl_xor((int)xd[0], 32);
    unsigned int px1 = (unsigned int)__shfl_xor((int)xd[1], 32);
    unsigned int py0 = (unsigned int)__shfl_xor((int)yd[0], 32);
    unsigned int py1 = (unsigned int)__shfl_xor((int)yd[1], 32);
    uint4v st;
    st[0] = h ? py0 : xd[0];
    st[1] = h ? py1 : xd[1];
    st[2] = h ? yd[0] : px0;
    st[3] = h ? yd[1] : px1;
    return st;
}

// ---------------------------------------------------------------------------
// K1: QKV GEMM. grid (128 n-tiles, 4 b), block 640 (10 waves; 5 waves/SIMD
// at 2 blocks/CU). Wave w owns exactly ONE output chain mb=w:
//   w0 -> q, w1 -> k, w2..9 -> v cblk (w-2).
// Stage: first 512 threads, 16 scalar loads each (2x128B segs per wave op).
// V exits via XOR-swizzled xf-LDS bounce -> dense b128 vh writes.
// ---------------------------------------------------------------------------
__global__ __launch_bounds__(640, 4) void qkv_kernel(
    const float* __restrict__ x, const unsigned short* __restrict__ What,
    unsigned short* __restrict__ qh, unsigned short* __restrict__ kh,
    unsigned short* __restrict__ vh)
{
    __shared__ __align__(16) unsigned short xf[16 * 512];  // 16 KB; reused for V

    const int t = threadIdx.x;
    const int w = t >> 6;          // 0..9
    const int l = t & 63;
    const int l31 = l & 31;
    const int h = l >> 5;
    const int nt = blockIdx.x, b = blockIdx.y;
    const int n0 = nt * 32;

    // ---- stage: threads 0..511; thread (n = t&31, cq = t>>5 in [0,16)) ----
    if (t < 512) {
        const float* xb = x + (size_t)(b * CH) * NN + n0;
        const int n = t & 31;
        const int cq = t >> 5;           // 0..15
        #pragma unroll
        for (int p = 0; p < 4; ++p) {
            int c = p * 64 + cq * 4;
            float v0 = xb[(size_t)(c + 0) * NN + n];
            float v1 = xb[(size_t)(c + 1) * NN + n];
            float v2 = xb[(size_t)(c + 2) * NN + n];
            float v3 = xb[(size_t)(c + 3) * NN + n];
            ushort4v u4;
            u4[0] = f2bf(v0); u4[1] = f2bf(v1); u4[2] = f2bf(v2); u4[3] = f2bf(v3);
            int addr = ((4 * p + (cq >> 2)) * 64 + n + 32 * ((cq >> 1) & 1)) * 8
                       + 4 * (cq & 1);
            *(ushort4v*)&xf[addr] = u4;
        }
    }
    __syncthreads();

    floatx16 acc;
    #pragma unroll
    for (int i = 0; i < 16; ++i) acc[i] = 0.f;

    for (int kblk = 0; kblk < 16; ++kblk) {
        bf16x8 bf = *(const bf16x8*)&xf[kblk * 512 + l * 8];
        bf16x8 af = *(const bf16x8*)(What + ((size_t)(w * 16 + kblk) * 64 + l) * 8);
        acc = __builtin_amdgcn_mfma_f32_32x32x16_bf16(af, bf, acc, 0, 0, 0);
    }

    // q/k: full-line b128 stores via h-exchange (layout bit-identical)
    auto store_qk = [&](unsigned short* dst, const floatx16& a) {
        size_t base = (size_t)(b * 128 + nt) * 1024;
        #pragma unroll
        for (int sb = 0; sb < 2; ++sb) {
            ushort4v xp, yp;
            #pragma unroll
            for (int i = 0; i < 4; ++i) {
                xp[i] = f2bf(a[8 * sb + i]);
                yp[i] = f2bf(a[8 * sb + 4 + i]);
            }
            uint4v st = hmerge(xp, yp, h);
            *(uint4v*)(dst + base + (size_t)sb * 512 + (size_t)l * 8) = st;
        }
    };

    if (w == 0)      store_qk(qh, acc);
    else if (w == 1) store_qk(kh, acc);

    __syncthreads();   // all xf (GEMM B-frag) reads done; reuse xf for V

    // v staged to LDS in vh-chunk layout with XOR bank swizzle.
    if (w >= 2) {
        const int cblk = w - 2;
        const int chunk = cblk * 2 + (l31 >> 4);
        const int hib = (l31 >> 3) & 1;
        #pragma unroll
        for (int r = 0; r < 16; ++r) {
            int rowo = (r & 3) + 8 * (r >> 2) + 4 * h;
            int unit = chunk * 64 + hib * 32 + rowo;
            int pu = unit ^ ((unit >> 5) & 7);
            xf[pu * 8 + (l31 & 7)] = f2bf(acc[r]);
        }
    }

    __syncthreads();

    // copy LDS -> vh: 16 chunks x 1KB, each contiguous in global. Dense b128.
    if (t < 512) {
        #pragma unroll
        for (int p = 0; p < 2; ++p) {
            int Lu = p * 512 + t;             // logical unit 0..1023
            int pu = Lu ^ ((Lu >> 5) & 7);
            uint4v d = *(const uint4v*)&xf[pu * 8];
            int chunk = Lu >> 6;
            int cblk = chunk >> 1, sub = chunk & 1;
            size_t dst = (((size_t)b * 8 + cblk) * 256 + nt * 2 + sub) * 512
                         + (size_t)(Lu & 63) * 8;
            *(uint4v*)(vh + dst) = d;
        }
    }
}

// ---------------------------------------------------------------------------
// K2: flash attention (FROZEN at R5). Q-tile 64, 8 waves, key-split 2.
// grid (64 qt-pairs, 2 ks, 4 b) = 512 blocks; XCD remap combo = lin&7.
// Fixed-shift softmax P = 2^(S-12); one barrier/iter; 16 its.
// ---------------------------------------------------------------------------
#define SM_M0 12.0f

__global__ __launch_bounds__(512, 4) void attn_kernel(
    const unsigned short* __restrict__ qh, const unsigned short* __restrict__ kh,
    const unsigned short* __restrict__ vh, unsigned short* __restrict__ Opart,
    float* __restrict__ ml)
{
    __shared__ unsigned short p_lds[2 * 16 * 64 * 8];   // 32 KB, double-buffered
    __shared__ float psum_s[8][32];

    const int t = threadIdx.x;
    const int w = t >> 6;          // 0..7
    const int l = t & 63;
    const int l31 = l & 31;
    const int h = l >> 5;
    const int wk = w & 3;          // key sub-slice
    const int hq = w >> 2;         // q-half for S phase

    const int lin = blockIdx.x + ((int)blockIdx.y << 6) + ((int)blockIdx.z << 7);
    const int combo = lin & 7;
    const int gp = lin >> 3;                          // 0..63 qt-pair
    const int ks = combo & 1;
    const int b  = combo >> 1;
    const int g0 = 2 * gp, g1 = 2 * gp + 1;

    const unsigned short* qB = qh + (size_t)(b * 128 + (hq ? g1 : g0)) * 1024;
    const unsigned short* kB = kh + (size_t)b * 128 * 1024;
    const unsigned short* vB = vh + (size_t)b * 8 * 256 * 512;

    bf16x8 qf0 = *(const bf16x8*)(qB + l * 8);
    bf16x8 qf1 = *(const bf16x8*)(qB + 512 + l * 8);

    bf16x8 kf0 = *(const bf16x8*)(kB + (size_t)(ks * 64 + wk) * 1024 + l * 8);
    bf16x8 kf1 = *(const bf16x8*)(kB + (size_t)(ks * 64 + wk) * 1024 + 512 + l * 8);

    float l_loc = 0.f;
    floatx16 acc_a, acc_b;        // cblk w, q-halves a/b
    #pragma unroll
    for (int i = 0; i < 16; ++i) { acc_a[i] = 0.f; acc_b[i] = 0.f; }

    for (int it = 0; it < 16; ++it) {
        const int pbase = (it & 1) << 13;            // 8192 ushorts per buffer

        floatx16 sacc;
        #pragma unroll
        for (int i = 0; i < 16; ++i) sacc[i] = 0.f;
        __builtin_amdgcn_s_setprio(1);
        sacc = __builtin_amdgcn_mfma_f32_32x32x16_bf16(kf0, qf0, sacc, 0, 0, 0);
        sacc = __builtin_amdgcn_mfma_f32_32x32x16_bf16(kf1, qf1, sacc, 0, 0, 0);
        __builtin_amdgcn_s_setprio(0);

        float pv[16];
        #pragma unroll
        for (int r = 0; r < 16; ++r) pv[r] = __builtin_exp2f(sacc[r] - SM_M0);
        float s0 = (pv[0] + pv[1]) + (pv[2] + pv[3]);
        float s1 = (pv[4] + pv[5]) + (pv[6] + pv[7]);
        float s2 = (pv[8] + pv[9]) + (pv[10] + pv[11]);
        float s3 = (pv[12] + pv[13]) + (pv[14] + pv[15]);
        l_loc += (s0 + s1) + (s2 + s3);
        #pragma unroll
        for (int rg = 0; rg < 4; ++rg) {
            ushort4v pk;
            #pragma unroll
            for (int i = 0; i < 4; ++i) pk[i] = f2bf(pv[rg * 4 + i]);
            int idx = pbase
                    + ((hq * 8 + 2 * wk + (rg >> 1)) * 64
                       + l31 + 32 * (rg & 1)) * 8 + 4 * h;
            *(ushort4v*)&p_lds[idx] = pk;
        }
        if (it < 15) {
            const unsigned short* kn = kB + (size_t)(ks * 64 + (it + 1) * 4 + wk) * 1024;
            kf0 = *(const bf16x8*)(kn + l * 8);
            kf1 = *(const bf16x8*)(kn + 512 + l * 8);
        }
        const unsigned short* v0b = vB + ((size_t)w * 256 + (ks * 16 + it) * 8) * 512;
        bf16x8 va0 = *(const bf16x8*)(v0b + 0 * 512 + l * 8);
        bf16x8 va1 = *(const bf16x8*)(v0b + 1 * 512 + l * 8);
        bf16x8 va2 = *(const bf16x8*)(v0b + 2 * 512 + l * 8);
        bf16x8 va3 = *(const bf16x8*)(v0b + 3 * 512 + l * 8);
        bf16x8 va4 = *(const bf16x8*)(v0b + 4 * 512 + l * 8);
        bf16x8 va5 = *(const bf16x8*)(v0b + 5 * 512 + l * 8);
        bf16x8 va6 = *(const bf16x8*)(v0b + 6 * 512 + l * 8);
        bf16x8 va7 = *(const bf16x8*)(v0b + 7 * 512 + l * 8);

        __syncthreads();   // p_lds[pbase] visible; prev-buffer reads long done

        bf16x8 pa = *(const bf16x8*)&p_lds[pbase + l * 8];
        bf16x8 pb = *(const bf16x8*)&p_lds[pbase + 4096 + l * 8];
        #pragma unroll
        for (int s = 0; s < 8; ++s) {
            bf16x8 vcur = (s == 0) ? va0 : (s == 1) ? va1 : (s == 2) ? va2
                        : (s == 3) ? va3 : (s == 4) ? va4 : (s == 5) ? va5
                        : (s == 6) ? va6 : va7;
            bf16x8 pa_n, pb_n;
            if (s < 7) {
                pa_n = *(const bf16x8*)&p_lds[pbase + ((s + 1) * 64 + l) * 8];
                pb_n = *(const bf16x8*)&p_lds[pbase + 4096 + ((s + 1) * 64 + l) * 8];
            }
            __builtin_amdgcn_s_setprio(1);
            acc_a = __builtin_amdgcn_mfma_f32_32x32x16_bf16(vcur, pa, acc_a, 0, 0, 0);
            acc_b = __builtin_amdgcn_mfma_f32_32x32x16_bf16(vcur, pb, acc_b, 0, 0, 0);
            __builtin_amdgcn_s_setprio(0);
            pa = pa_n; pb = pb_n;
        }
    }

    float lt = l_loc + __shfl_xor(l_loc, 32);
    if (h == 0) psum_s[w][l31] = lt;
    __syncthreads();

    if (w == 0 && h == 0) {
        float l_run = (psum_s[0][l31] + psum_s[1][l31])
                    + (psum_s[2][l31] + psum_s[3][l31]);
        ml[((size_t)(b * 128 + g0) * 2 + ks) * 32 + l31] = l_run;
    }
    if (w == 4 && h == 0) {
        float l_run = (psum_s[4][l31] + psum_s[5][l31])
                    + (psum_s[6][l31] + psum_s[7][l31]);
        ml[((size_t)(b * 128 + g1) * 2 + ks) * 32 + l31] = l_run;
    }

    unsigned short* opa = Opart + ((size_t)((b * 128 + g0) * 2 + ks)) * 8192;
    unsigned short* opb = Opart + ((size_t)((b * 128 + g1) * 2 + ks)) * 8192;
    #pragma unroll
    for (int ct = 0; ct < 2; ++ct) {
        const floatx16& a = ct ? acc_b : acc_a;
        unsigned short* op = ct ? opb : opa;
        #pragma unroll
        for (int sb = 0; sb < 2; ++sb) {
            ushort4v xp, yp;
            #pragma unroll
            for (int i = 0; i < 4; ++i) {
                xp[i] = f2bf(a[8 * sb + i]);
                yp[i] = f2bf(a[8 * sb + 4 + i]);
            }
            uint4v st = hmerge(xp, yp, h);
            int sP = 2 * w + sb;
            *(uint4v*)(op + ((size_t)sP * 64 + l) * 8) = st;
        }
    }
}

// ---------------------------------------------------------------------------
// K3: Wo GEMM, m-split for TLP: grid (128 qt, 2 mhalf, 4 b) = 1024 blocks,
// 4 waves; wave owns m-tile mt = mhalf*4 + w with TWO exact MFMA chains
// (one per key-split partial, Opart bf16 straight to MFMA), then
// (a0+a1) * 1/(l0+l1) post-GEMM + gamma*out + x. ~70 VGPR, 4 waves/SIMD.
// mhalf twins: lin ids differ by 128 = 0 mod 8 -> same XCD, shared Opart L2.
// ---------------------------------------------------------------------------
__global__ __launch_bounds__(256, 4) void out_kernel(
    const unsigned short* __restrict__ Opart, const float* __restrict__ ml,
    const unsigned short* __restrict__ WobF, const float* __restrict__ x,
    const float* __restrict__ gamma, float* __restrict__ out)
{
    const int t = threadIdx.x;
    const int w = t >> 6;
    const int l = t & 63;
    const int l31 = l & 31;
    const int h = l >> 5;
    const int qt = blockIdx.x, mhalf = blockIdx.y, b = blockIdx.z;
    const int mt = mhalf * 4 + w;

    const size_t slot2 = (size_t)(b * 128 + qt) * 2;
    float l0 = ml[(slot2 + 0) * 32 + l31];
    float l1 = ml[(slot2 + 1) * 32 + l31];
    float rL = 1.0f / (l0 + l1);     // per-lane: D-layout col = l31 = query

    const unsigned short* o0 = Opart + (slot2 + 0) * 8192;
    const unsigned short* o1 = Opart + (slot2 + 1) * 8192;

    floatx16 a0, a1;
    #pragma unroll
    for (int i = 0; i < 16; ++i) { a0[i] = 0.f; a1[i] = 0.f; }

    for (int s = 0; s < 16; ++s) {
        bf16x8 f0 = *(const bf16x8*)(o0 + (s * 64 + l) * 8);
        bf16x8 f1 = *(const bf16x8*)(o1 + (s * 64 + l) * 8);
        bf16x8 af = *(const bf16x8*)(WobF + ((size_t)(mt * 16 + s) * 64 + l) * 8);
        a0 = __builtin_amdgcn_mfma_f32_32x32x16_bf16(af, f0, a0, 0, 0, 0);
        a1 = __builtin_amdgcn_mfma_f32_32x32x16_bf16(af, f1, a1, 0, 0, 0);
    }

    const float gm = gamma[0];
    #pragma unroll
    for (int r = 0; r < 16; ++r) {
        float v = (a0[r] + a1[r]) * rL;
        int o = mt * 32 + (r & 3) + 8 * (r >> 2) + 4 * h;
        int n = qt * 32 + l31;
        size_t oi = ((size_t)(b * 256 + o)) * NN + n;
        out[oi] = gm * v + x[oi];
    }
}

// ---------------------------------------------------------------------------
extern "C" void kernel_launch(void* const* d_in, const int* in_sizes, int n_in,
                              void* d_out, int out_size, void* d_ws, size_t ws_size,
                              hipStream_t stream)
{
    const float* x     = (const float*)d_in[0];
    const float* Wq    = (const float*)d_in[1];
    const float* Wk    = (const float*)d_in[2];
    const float* Wv    = (const float*)d_in[3];
    const float* Wo    = (const float*)d_in[4];
    const float* gamma = (const float*)d_in[5];
    float* out = (float*)d_out;

    char* wsb = (char*)d_ws;
    unsigned short* qh    = (unsigned short*)(wsb);                          // 1 MB
    unsigned short* kh    = (unsigned short*)(wsb + (1u << 20));             // 1 MB
    unsigned short* vh    = (unsigned short*)(wsb + (2u << 20));             // 8 MB
    unsigned short* What  = (unsigned short*)(wsb + (10u << 20));            // 160 KB
    unsigned short* WobF  = (unsigned short*)(wsb + (10u << 20) + (256u << 10)); // 128 KB
    unsigned short* Opart = (unsigned short*)(wsb + (11u << 20));            // 16.8 MB (ks=2)
    float*          ml    = (float*)         (wsb + (45u << 20));            // 128 KB

    wconv_kernel<<<320, 256, 0, stream>>>(Wq, Wk, Wv, Wo, What, WobF);

    dim3 g1(128, BATCH);
    qkv_kernel<<<g1, 640, 0, stream>>>(x, What, qh, kh, vh);

    dim3 g2(64, 2, BATCH);
    attn_kernel<<<g2, 512, 0, stream>>>(qh, kh, vh, Opart, ml);

    dim3 g3(128, 2, BATCH);
    out_kernel<<<g3, 256, 0, stream>>>(Opart, ml, WobF, x, gamma, out);
}